// Round 5
// baseline (279.055 us; speedup 1.0000x reference)
//
#include <hip/hip_runtime.h>
#include <hip/hip_bf16.h>

// EncoderLayer: B=4 S=1024 D=1024 H=16 DH=64 DFF=2048
// Round 4 (resubmit after GPU timeout): zero-LDS swapped-operand MFMA flash
// attention (K/V direct to regs, P via cvt_pk+ds_bpermute), FFN2 128x64 tile,
// XCD swizzle.
//
// ws layout (bytes):
//   qkvb bf16: q[64hb][1024][64] | k[...] | vT[64hb][64][1024]  @ 0   (24 MB)
//      (q pre-scaled by 0.125*log2e for exp2-domain softmax)
//   Xb    bf16 [4096][1024]             @ 24 MB (8 MB)
//   Wqkvt bf16 [3072][1024]  (B^T)      @ 32 MB (6 MB)
//   W1t   bf16 [2048][1024]  (B^T)      @ 38 MB (4 MB)
//   W2t   bf16 [1024][2048]  (B^T)      @ 42 MB (4 MB)
//   h1b   bf16 [4096][1024]             @ 46 MB (8 MB)
//   ffb   bf16 [4096][2048]             @ 54 MB (16 MB)  -> 70 MB total

typedef unsigned short u16;
typedef __attribute__((ext_vector_type(8))) short bfrag8;   // 8 bf16 = 4 VGPRs
typedef __attribute__((ext_vector_type(4))) float f32x4;
typedef __attribute__((ext_vector_type(4))) int ix4;

constexpr int Bb = 4, Ss = 1024, Dd = 1024, Hh = 16, DFF = 2048;
constexpr float QSCALE = 0.18033688011112042f;   // 0.125 * log2(e)

__device__ __forceinline__ u16 f2bf(float f) {
  unsigned u = __float_as_uint(f);
  return (u16)((u + 0x7fffu + ((u >> 16) & 1u)) >> 16);
}

__device__ __forceinline__ void gload16(const void* g, void* l) {
  __builtin_amdgcn_global_load_lds(
      (const __attribute__((address_space(1))) unsigned int*)g,
      (__attribute__((address_space(3))) unsigned int*)l, 16, 0, 0);
}

// chunked XCD swizzle: hw block id -> work id (grid size % 8 == 0)
__device__ __forceinline__ int xcd_swz() {
  const int id = blockIdx.y * gridDim.x + blockIdx.x;
  const int cpx = (gridDim.x * gridDim.y) >> 3;
  return (id & 7) * cpx + (id >> 3);
}

// ---------------------------------------------------------------------------
__global__ __launch_bounds__(256) void cvt_bf16(const float* __restrict__ in,
                                                u16* __restrict__ out, int n4) {
  int i = blockIdx.x * 256 + threadIdx.x;
  if (i >= n4) return;
  float4 v = ((const float4*)in)[i];
  ushort4 o = make_ushort4(f2bf(v.x), f2bf(v.y), f2bf(v.z), f2bf(v.w));
  *(ushort4*)(out + (size_t)i * 4) = o;
}

__device__ __forceinline__ void transpose64(const float* __restrict__ in,
                                            u16* __restrict__ out,
                                            int R, int C, int r0, int c0) {
  __shared__ float tile[64][65];
  const int t = threadIdx.x, cl = t & 63, rq = t >> 6;
#pragma unroll
  for (int i = 0; i < 16; ++i) {
    int rl = rq * 16 + i;
    tile[rl][cl] = in[(size_t)(r0 + rl) * C + c0 + cl];
  }
  __syncthreads();
#pragma unroll
  for (int i = 0; i < 16; ++i) {
    int oc = rq * 16 + i;
    out[(size_t)(c0 + oc) * R + r0 + cl] = f2bf(tile[cl][oc]);
  }
}

__global__ __launch_bounds__(256) void transpose_cvt(const float* __restrict__ in,
                                                     u16* __restrict__ out,
                                                     int R, int C) {
  transpose64(in, out, R, C, blockIdx.x * 64, blockIdx.y * 64);
}

__global__ __launch_bounds__(256) void qkv_transpose_cvt(
    const float* __restrict__ Wq, const float* __restrict__ Wk,
    const float* __restrict__ Wv, u16* __restrict__ out) {
  const int z = blockIdx.y;            // 0..47
  const int which = z >> 4, h = z & 15;
  const float* in = (which == 0 ? Wq : which == 1 ? Wk : Wv) + (size_t)h * 1024 * 64;
  u16* o = out + (size_t)z * 64 * 1024;
  transpose64(in, o, 1024, 64, blockIdx.x * 64, 0);
}

// ---------------------------------------------------------------------------
// bf16 MFMA GEMM, 128x128 tile, BK=32, 4 waves x (64x64).
// EPI 0: scatter bf16 q(scaled)/k/vT; 1: +bias,relu -> bf16; 2: +bias -> fp32.
// ---------------------------------------------------------------------------
template <int EPI>
__global__ __launch_bounds__(256) void mfma_gemm(
    const u16* __restrict__ A, const u16* __restrict__ Bt,
    const float* __restrict__ bias, void* __restrict__ Cout, int N, int K) {
  __shared__ alignas(16) u16 Asm[128 * 32];   // [row][k], row stride 64 B
  __shared__ alignas(16) u16 Bsm[128 * 32];
  const int tid = threadIdx.x;
  const int wid = tid >> 6, lane = tid & 63;
  const int nid = xcd_swz();
  const int m0 = (nid / gridDim.x) * 128, n0 = (nid % gridDim.x) * 128;
  const int wr = wid >> 1, wc = wid & 1;
  const int fr = lane & 15, krow = lane >> 4;

  const int srow = tid >> 2;
  const int sk = (tid & 3) * 8;
  const u16* ga0 = A + (size_t)(m0 + srow) * K + sk;
  const u16* ga1 = A + (size_t)(m0 + srow + 64) * K + sk;
  const u16* gb0 = Bt + (size_t)(n0 + srow) * K + sk;
  const u16* gb1 = Bt + (size_t)(n0 + srow + 64) * K + sk;
  char* lA0 = (char*)Asm + tid * 16;
  char* lA1 = lA0 + 4096;
  char* lB0 = (char*)Bsm + tid * 16;
  char* lB1 = lB0 + 4096;

  f32x4 acc[4][4];
#pragma unroll
  for (int i = 0; i < 4; ++i)
#pragma unroll
    for (int j = 0; j < 4; ++j) acc[i][j] = (f32x4){0.f, 0.f, 0.f, 0.f};

  const char* pa = (const char*)Asm + (wr * 64 + fr) * 64 + krow * 16;
  const char* pb = (const char*)Bsm + (wc * 64 + fr) * 64 + krow * 16;

  for (int kt = 0; kt < K / 32; ++kt) {
    __syncthreads();
    gload16(ga0 + kt * 32, lA0);
    gload16(ga1 + kt * 32, lA1);
    gload16(gb0 + kt * 32, lB0);
    gload16(gb1 + kt * 32, lB1);
    __syncthreads();

    bfrag8 af[4], bfv[4];
#pragma unroll
    for (int i = 0; i < 4; ++i) af[i] = *(const bfrag8*)(pa + i * 1024);
#pragma unroll
    for (int j = 0; j < 4; ++j) bfv[j] = *(const bfrag8*)(pb + j * 1024);
#pragma unroll
    for (int i = 0; i < 4; ++i)
#pragma unroll
      for (int j = 0; j < 4; ++j)
        acc[i][j] = __builtin_amdgcn_mfma_f32_16x16x32_bf16(af[i], bfv[j], acc[i][j], 0, 0, 0);
  }

  const int orow = (lane >> 4) * 4;
  const int ocol = lane & 15;
#pragma unroll
  for (int i = 0; i < 4; ++i) {
#pragma unroll
    for (int j = 0; j < 4; ++j) {
      const int gn = n0 + wc * 64 + j * 16 + ocol;
      const int gm0 = m0 + wr * 64 + i * 16 + orow;
      if (EPI == 0) {
        const int which = gn >> 10, hh = (gn >> 6) & 15, e = gn & 63;
        const int bb = gm0 >> 10, s0 = gm0 & 1023;
        const int hb = hh * 4 + bb;
        u16* oq = (u16*)Cout;
        if (which == 0) {
#pragma unroll
          for (int r = 0; r < 4; ++r)
            oq[((size_t)hb * 1024 + s0 + r) * 64 + e] = f2bf(acc[i][j][r] * QSCALE);
        } else if (which == 1) {
#pragma unroll
          for (int r = 0; r < 4; ++r)
            oq[4194304 + ((size_t)hb * 1024 + s0 + r) * 64 + e] = f2bf(acc[i][j][r]);
        } else {
          ushort4 pk = make_ushort4(f2bf(acc[i][j][0]), f2bf(acc[i][j][1]),
                                    f2bf(acc[i][j][2]), f2bf(acc[i][j][3]));
          *(ushort4*)&oq[8388608 + ((size_t)hb * 64 + e) * 1024 + s0] = pk;
        }
      } else if (EPI == 1) {
#pragma unroll
        for (int r = 0; r < 4; ++r) {
          float v = fmaxf(acc[i][j][r] + bias[gn], 0.f);
          ((u16*)Cout)[(size_t)(gm0 + r) * N + gn] = f2bf(v);
        }
      } else {
#pragma unroll
        for (int r = 0; r < 4; ++r)
          ((float*)Cout)[(size_t)(gm0 + r) * N + gn] = acc[i][j][r] + bias[gn];
      }
    }
  }
}

// ---------------------------------------------------------------------------
// bf16 MFMA GEMM, 128x64 tile (for small-N FFN2): 4 waves x (32x64), BK=32.
// EPI 2 only: +bias -> fp32.
// ---------------------------------------------------------------------------
__global__ __launch_bounds__(256) void mfma_gemm_n64(
    const u16* __restrict__ A, const u16* __restrict__ Bt,
    const float* __restrict__ bias, float* __restrict__ Cout, int N, int K) {
  __shared__ alignas(16) u16 Asm[128 * 32];
  __shared__ alignas(16) u16 Bsm[64 * 32];
  const int tid = threadIdx.x;
  const int wid = tid >> 6, lane = tid & 63;
  const int nid = xcd_swz();
  const int m0 = (nid / gridDim.x) * 128, n0 = (nid % gridDim.x) * 64;
  const int fr = lane & 15, krow = lane >> 4;

  const int srow = tid >> 2;
  const int sk = (tid & 3) * 8;
  const u16* ga0 = A + (size_t)(m0 + srow) * K + sk;
  const u16* ga1 = A + (size_t)(m0 + srow + 64) * K + sk;
  const u16* gb0 = Bt + (size_t)(n0 + srow) * K + sk;
  char* lA0 = (char*)Asm + tid * 16;
  char* lA1 = lA0 + 4096;
  char* lB0 = (char*)Bsm + tid * 16;

  f32x4 acc[2][4];
#pragma unroll
  for (int i = 0; i < 2; ++i)
#pragma unroll
    for (int j = 0; j < 4; ++j) acc[i][j] = (f32x4){0.f, 0.f, 0.f, 0.f};

  const char* pa = (const char*)Asm + (wid * 32 + fr) * 64 + krow * 16;
  const char* pb = (const char*)Bsm + fr * 64 + krow * 16;

  for (int kt = 0; kt < K / 32; ++kt) {
    __syncthreads();
    gload16(ga0 + kt * 32, lA0);
    gload16(ga1 + kt * 32, lA1);
    gload16(gb0 + kt * 32, lB0);
    __syncthreads();

    bfrag8 af[2], bfv[4];
#pragma unroll
    for (int i = 0; i < 2; ++i) af[i] = *(const bfrag8*)(pa + i * 1024);
#pragma unroll
    for (int j = 0; j < 4; ++j) bfv[j] = *(const bfrag8*)(pb + j * 1024);
#pragma unroll
    for (int i = 0; i < 2; ++i)
#pragma unroll
      for (int j = 0; j < 4; ++j)
        acc[i][j] = __builtin_amdgcn_mfma_f32_16x16x32_bf16(af[i], bfv[j], acc[i][j], 0, 0, 0);
  }

  const int orow = (lane >> 4) * 4;
  const int ocol = lane & 15;
#pragma unroll
  for (int i = 0; i < 2; ++i)
#pragma unroll
    for (int j = 0; j < 4; ++j) {
      const int gn = n0 + j * 16 + ocol;
      const int gm0 = m0 + wid * 32 + i * 16 + orow;
#pragma unroll
      for (int r = 0; r < 4; ++r)
        Cout[(size_t)(gm0 + r) * N + gn] = acc[i][j][r] + bias[gn];
    }
}

// ---------------------------------------------------------------------------
// Zero-LDS swapped-operand MFMA flash attention.
// Wave = 32 queries; block = 4 waves (128 q-rows); grid = (8, 64) swizzled.
// All operands global->regs; P stays in regs via cvt_pk + ds_bpermute.
// Layouts (16x16x32, verified m89/m91):
//   QK^T swapped: sc2[m][kn] = mfma(K_frag[kn], Q_frag[m]) = P^T fragment:
//     lane(fr,hi) holds P[key = kn*16+hi*4+r][query = m*16+fr]
//   PV swapped:   acc2[m][en] = mfma(V_frag[en], P_frag[m]) = O^T fragment:
//     lane(fr,hi) holds O[query = m*16+fr][e = en*16+hi*4+r]
// ---------------------------------------------------------------------------
__global__ __launch_bounds__(256, 2) void attn_mfma(
    const u16* __restrict__ qb, const u16* __restrict__ kb,
    const u16* __restrict__ vtb, u16* __restrict__ h1) {
  const int tid = threadIdx.x, wid = tid >> 6, lane = tid & 63;
  const int nid = xcd_swz();
  const int qx = nid & 7, hb = nid >> 3;
  const int h = hb >> 2, b = hb & 3;
  const int q0 = qx * 128 + wid * 32;
  const int fr = lane & 15, hi = lane >> 4;

  const u16* Qg = qb + ((size_t)hb * 1024 + q0) * 64;
  const u16* Kg = kb + (size_t)hb * 1024 * 64;
  const u16* Vg = vtb + (size_t)hb * 64 * 1024;

  // Q fragments (b-operand, rows = q): pre-scaled by 0.125*log2e
  bfrag8 qf[2][2];
#pragma unroll
  for (int m = 0; m < 2; ++m)
#pragma unroll
    for (int kk = 0; kk < 2; ++kk)
      qf[m][kk] = *(const bfrag8*)(Qg + (m * 16 + fr) * 64 + kk * 32 + hi * 8);

  f32x4 acc2[2][4];
#pragma unroll
  for (int m = 0; m < 2; ++m)
#pragma unroll
    for (int en = 0; en < 4; ++en) acc2[m][en] = (f32x4){0.f, 0.f, 0.f, 0.f};
  float mrun[2] = {-1e30f, -1e30f}, lrun[2] = {0.f, 0.f};

  // bpermute sources: srcA = fr + 32*(hi&1), srcB = srcA + 16 (byte addrs)
  const int addrA = ((lane & 15) + ((lane & 16) << 1)) << 2;
  const int addrB = addrA + 64;
  const bool hiSel = (lane >= 32);     // hi>>1

  bfrag8 kfA[4][2], vfA[4][2], kfB[4][2], vfB[4][2];

#define LOAD_KV(kf, vf, kt)                                                    \
  {                                                                            \
    _Pragma("unroll") for (int kn = 0; kn < 4; ++kn)                           \
        _Pragma("unroll") for (int kk = 0; kk < 2; ++kk) {                     \
      kf[kn][kk] = *(const bfrag8*)(Kg + (size_t)((kt)*64 + kn * 16 + fr) * 64 \
                                    + kk * 32 + hi * 8);                       \
      vf[kn][kk] = *(const bfrag8*)(Vg + (size_t)(kn * 16 + fr) * 1024         \
                                    + (kt)*64 + kk * 32 + hi * 8);             \
    }                                                                          \
  }

#define TILE_STEP(kf, vf)                                                      \
  {                                                                            \
    f32x4 sc2[2][4];                                                           \
    __builtin_amdgcn_s_setprio(1);                                             \
    _Pragma("unroll") for (int m = 0; m < 2; ++m)                              \
        _Pragma("unroll") for (int kn = 0; kn < 4; ++kn) {                     \
      f32x4 t = (f32x4){0.f, 0.f, 0.f, 0.f};                                   \
      t = __builtin_amdgcn_mfma_f32_16x16x32_bf16(kf[kn][0], qf[m][0], t, 0, 0, 0); \
      t = __builtin_amdgcn_mfma_f32_16x16x32_bf16(kf[kn][1], qf[m][1], t, 0, 0, 0); \
      sc2[m][kn] = t;                                                          \
    }                                                                          \
    __builtin_amdgcn_s_setprio(0);                                             \
    int pk[2][4][2];                                                           \
    _Pragma("unroll") for (int m = 0; m < 2; ++m) {                            \
      float cm = -1e30f;                                                       \
      _Pragma("unroll") for (int kn = 0; kn < 4; ++kn)                         \
          _Pragma("unroll") for (int r = 0; r < 4; ++r)                        \
              cm = fmaxf(cm, sc2[m][kn][r]);                                   \
      cm = fmaxf(cm, __shfl_xor(cm, 16));                                      \
      cm = fmaxf(cm, __shfl_xor(cm, 32));                                      \
      const float mnew = fmaxf(mrun[m], cm);                                   \
      const float scl = exp2f(mrun[m] - mnew);                                 \
      mrun[m] = mnew;                                                          \
      float psum = 0.f;                                                        \
      float p[4][4];                                                           \
      _Pragma("unroll") for (int kn = 0; kn < 4; ++kn)                         \
          _Pragma("unroll") for (int r = 0; r < 4; ++r) {                      \
        p[kn][r] = exp2f(sc2[m][kn][r] - mnew);                                \
        psum += p[kn][r];                                                      \
      }                                                                        \
      psum += __shfl_xor(psum, 16);                                            \
      psum += __shfl_xor(psum, 32);                                            \
      lrun[m] = lrun[m] * scl + psum;                                          \
      _Pragma("unroll") for (int en = 0; en < 4; ++en)                         \
          acc2[m][en] = acc2[m][en] * scl;                                     \
      _Pragma("unroll") for (int kn = 0; kn < 4; ++kn) {                       \
        asm("v_cvt_pk_bf16_f32 %0, %1, %2"                                     \
            : "=v"(pk[m][kn][0]) : "v"(p[kn][0]), "v"(p[kn][1]));              \
        asm("v_cvt_pk_bf16_f32 %0, %1, %2"                                     \
            : "=v"(pk[m][kn][1]) : "v"(p[kn][2]), "v"(p[kn][3]));              \
      }                                                                        \
    }                                                                          \
    bfrag8 pfrag[2][2];                                                        \
    _Pragma("unroll") for (int m = 0; m < 2; ++m)                              \
        _Pragma("unroll") for (int kk = 0; kk < 2; ++kk) {                     \
      int w[4];                                                                \
      _Pragma("unroll") for (int wi = 0; wi < 2; ++wi) {                       \
        int t0 = __builtin_amdgcn_ds_bpermute(addrA, pk[m][2 * kk][wi]);       \
        int t1 = __builtin_amdgcn_ds_bpermute(addrA, pk[m][2 * kk + 1][wi]);   \
        w[wi] = hiSel ? t1 : t0;                                               \
        t0 = __builtin_amdgcn_ds_bpermute(addrB, pk[m][2 * kk][wi]);           \
        t1 = __builtin_amdgcn_ds_bpermute(addrB, pk[m][2 * kk + 1][wi]);       \
        w[2 + wi] = hiSel ? t1 : t0;                                           \
      }                                                                        \
      ix4 tmp = (ix4){w[0], w[1], w[2], w[3]};                                 \
      pfrag[m][kk] = __builtin_bit_cast(bfrag8, tmp);                          \
    }                                                                          \
    __builtin_amdgcn_s_setprio(1);                                             \
    _Pragma("unroll") for (int m = 0; m < 2; ++m)                              \
        _Pragma("unroll") for (int en = 0; en < 4; ++en) {                     \
      acc2[m][en] = __builtin_amdgcn_mfma_f32_16x16x32_bf16(                   \
          vf[en][0], pfrag[m][0], acc2[m][en], 0, 0, 0);                       \
      acc2[m][en] = __builtin_amdgcn_mfma_f32_16x16x32_bf16(                   \
          vf[en][1], pfrag[m][1], acc2[m][en], 0, 0, 0);                       \
    }                                                                          \
    __builtin_amdgcn_s_setprio(0);                                             \
  }

  LOAD_KV(kfA, vfA, 0);
  for (int kt = 0; kt < 16; kt += 2) {
    if (kt + 1 < 16) LOAD_KV(kfB, vfB, kt + 1);
    TILE_STEP(kfA, vfA);
    if (kt + 2 < 16) LOAD_KV(kfA, vfA, kt + 2);
    TILE_STEP(kfB, vfB);
  }

  // epilogue: O[q][e], e contiguous per reg quad -> ushort4 stores
#pragma unroll
  for (int m = 0; m < 2; ++m) {
    const float inv = 1.f / lrun[m];
    const int s = q0 + m * 16 + fr;
    u16* op = h1 + ((size_t)(b * 1024 + s)) * 1024 + h * 64 + hi * 4;
#pragma unroll
    for (int en = 0; en < 4; ++en) {
      ushort4 o = make_ushort4(
          f2bf(acc2[m][en][0] * inv), f2bf(acc2[m][en][1] * inv),
          f2bf(acc2[m][en][2] * inv), f2bf(acc2[m][en][3] * inv));
      *(ushort4*)(op + en * 16) = o;
    }
  }
#undef LOAD_KV
#undef TILE_STEP
}

// ---------------------------------------------------------------------------
extern "C" void kernel_launch(void* const* d_in, const int* in_sizes, int n_in,
                              void* d_out, int out_size, void* d_ws, size_t ws_size,
                              hipStream_t stream) {
  const float* x  = (const float*)d_in[0];
  const float* Wq = (const float*)d_in[1];
  const float* Wk = (const float*)d_in[2];
  const float* Wv = (const float*)d_in[3];
  const float* W1 = (const float*)d_in[4];
  const float* b1 = (const float*)d_in[5];
  const float* W2 = (const float*)d_in[6];
  const float* b2 = (const float*)d_in[7];

  const size_t MB = 1u << 20;
  char* w = (char*)d_ws;
  u16* qkvb  = (u16*)w;                    // 24 MB: q | k | vT
  u16* Xb    = (u16*)(w + 24 * MB);
  u16* Wqkvt = (u16*)(w + 32 * MB);
  u16* W1t   = (u16*)(w + 38 * MB);
  u16* W2t   = (u16*)(w + 42 * MB);
  u16* h1b   = (u16*)(w + 46 * MB);
  u16* ffb   = (u16*)(w + 54 * MB);

  cvt_bf16<<<4096, 256, 0, stream>>>(x, Xb, 1048576);
  qkv_transpose_cvt<<<dim3(16, 48), 256, 0, stream>>>(Wq, Wk, Wv, Wqkvt);
  transpose_cvt<<<dim3(16, 32), 256, 0, stream>>>(W1, W1t, 1024, 2048);
  transpose_cvt<<<dim3(32, 16), 256, 0, stream>>>(W2, W2t, 2048, 1024);

  // QKV: [4096,1024] @ [1024,3072] -> bf16 q(scaled)/k/vT scatter
  mfma_gemm<0><<<dim3(24, 32), 256, 0, stream>>>(Xb, Wqkvt, nullptr, qkvb, 3072, 1024);
  // attention -> h1b bf16 [4096][1024]
  attn_mfma<<<dim3(8, 64), 256, 0, stream>>>(qkvb, qkvb + 4194304, qkvb + 8388608, h1b);
  // FFN1: relu(h1 @ W1 + b1) -> ffb bf16 [4096][2048]
  mfma_gemm<1><<<dim3(16, 32), 256, 0, stream>>>(h1b, W1t, b1, ffb, 2048, 1024);
  // FFN2: ff @ W2 + b2 -> out fp32 [4096][1024], 128x64 tiles (2 blk/CU)
  mfma_gemm_n64<<<dim3(16, 32), 256, 0, stream>>>(ffb, W2t, b2, (float*)d_out, 1024, 2048);
}

// Round 6
// 275.074 us; speedup vs baseline: 1.0145x; 1.0145x over previous
//
#include <hip/hip_runtime.h>
#include <hip/hip_bf16.h>

// EncoderLayer: B=4 S=1024 D=1024 H=16 DH=64 DFF=2048
// Round 6: 32x32x16 swapped-operand flash attention, softmax fully in-register
// (one query per lane), P exchange via v_cvt_pk_bf16_f32 + v_permlane32_swap
// (VALU, replaces round-4's 32 ds_bpermute). Zero LDS, zero barriers in attn.
//
// ws layout (bytes):
//   qkvb bf16: q[64hb][1024][64] | k[...] | vT[64hb][64][1024]  @ 0   (24 MB)
//      (q pre-scaled by 0.125*log2e for exp2-domain softmax)
//   Xb    bf16 [4096][1024]             @ 24 MB (8 MB)
//   Wqkvt bf16 [3072][1024]  (B^T)      @ 32 MB (6 MB)
//   W1t   bf16 [2048][1024]  (B^T)      @ 38 MB (4 MB)
//   W2t   bf16 [1024][2048]  (B^T)      @ 42 MB (4 MB)
//   h1b   bf16 [4096][1024]             @ 46 MB (8 MB)
//   ffb   bf16 [4096][2048]             @ 54 MB (16 MB)  -> 70 MB total

typedef unsigned short u16;
typedef __attribute__((ext_vector_type(8))) short bfrag8;    // 8 bf16 = 4 VGPRs
typedef __attribute__((ext_vector_type(4))) float f32x4;
typedef __attribute__((ext_vector_type(16))) float f32x16;
typedef __attribute__((ext_vector_type(4))) int ix4;

constexpr int Bb = 4, Ss = 1024, Dd = 1024, Hh = 16, DFF = 2048;
constexpr float QSCALE = 0.18033688011112042f;   // 0.125 * log2(e)

__device__ __forceinline__ u16 f2bf(float f) {
  unsigned u = __float_as_uint(f);
  return (u16)((u + 0x7fffu + ((u >> 16) & 1u)) >> 16);
}

__device__ __forceinline__ void gload16(const void* g, void* l) {
  __builtin_amdgcn_global_load_lds(
      (const __attribute__((address_space(1))) unsigned int*)g,
      (__attribute__((address_space(3))) unsigned int*)l, 16, 0, 0);
}

// chunked XCD swizzle: hw block id -> work id (grid size % 8 == 0)
__device__ __forceinline__ int xcd_swz() {
  const int id = blockIdx.y * gridDim.x + blockIdx.x;
  const int cpx = (gridDim.x * gridDim.y) >> 3;
  return (id & 7) * cpx + (id >> 3);
}

// ---------------------------------------------------------------------------
__global__ __launch_bounds__(256) void cvt_bf16(const float* __restrict__ in,
                                                u16* __restrict__ out, int n4) {
  int i = blockIdx.x * 256 + threadIdx.x;
  if (i >= n4) return;
  float4 v = ((const float4*)in)[i];
  ushort4 o = make_ushort4(f2bf(v.x), f2bf(v.y), f2bf(v.z), f2bf(v.w));
  *(ushort4*)(out + (size_t)i * 4) = o;
}

__device__ __forceinline__ void transpose64(const float* __restrict__ in,
                                            u16* __restrict__ out,
                                            int R, int C, int r0, int c0) {
  __shared__ float tile[64][65];
  const int t = threadIdx.x, cl = t & 63, rq = t >> 6;
#pragma unroll
  for (int i = 0; i < 16; ++i) {
    int rl = rq * 16 + i;
    tile[rl][cl] = in[(size_t)(r0 + rl) * C + c0 + cl];
  }
  __syncthreads();
#pragma unroll
  for (int i = 0; i < 16; ++i) {
    int oc = rq * 16 + i;
    out[(size_t)(c0 + oc) * R + r0 + cl] = f2bf(tile[cl][oc]);
  }
}

__global__ __launch_bounds__(256) void transpose_cvt(const float* __restrict__ in,
                                                     u16* __restrict__ out,
                                                     int R, int C) {
  transpose64(in, out, R, C, blockIdx.x * 64, blockIdx.y * 64);
}

__global__ __launch_bounds__(256) void qkv_transpose_cvt(
    const float* __restrict__ Wq, const float* __restrict__ Wk,
    const float* __restrict__ Wv, u16* __restrict__ out) {
  const int z = blockIdx.y;            // 0..47
  const int which = z >> 4, h = z & 15;
  const float* in = (which == 0 ? Wq : which == 1 ? Wk : Wv) + (size_t)h * 1024 * 64;
  u16* o = out + (size_t)z * 64 * 1024;
  transpose64(in, o, 1024, 64, blockIdx.x * 64, 0);
}

// ---------------------------------------------------------------------------
// bf16 MFMA GEMM, 128x128 tile, BK=32, 4 waves x (64x64).
// EPI 0: scatter bf16 q(scaled)/k/vT; 1: +bias,relu -> bf16; 2: +bias -> fp32.
// ---------------------------------------------------------------------------
template <int EPI>
__global__ __launch_bounds__(256) void mfma_gemm(
    const u16* __restrict__ A, const u16* __restrict__ Bt,
    const float* __restrict__ bias, void* __restrict__ Cout, int N, int K) {
  __shared__ alignas(16) u16 Asm[128 * 32];   // [row][k], row stride 64 B
  __shared__ alignas(16) u16 Bsm[128 * 32];
  const int tid = threadIdx.x;
  const int wid = tid >> 6, lane = tid & 63;
  const int nid = xcd_swz();
  const int m0 = (nid / gridDim.x) * 128, n0 = (nid % gridDim.x) * 128;
  const int wr = wid >> 1, wc = wid & 1;
  const int fr = lane & 15, krow = lane >> 4;

  const int srow = tid >> 2;
  const int sk = (tid & 3) * 8;
  const u16* ga0 = A + (size_t)(m0 + srow) * K + sk;
  const u16* ga1 = A + (size_t)(m0 + srow + 64) * K + sk;
  const u16* gb0 = Bt + (size_t)(n0 + srow) * K + sk;
  const u16* gb1 = Bt + (size_t)(n0 + srow + 64) * K + sk;
  char* lA0 = (char*)Asm + tid * 16;
  char* lA1 = lA0 + 4096;
  char* lB0 = (char*)Bsm + tid * 16;
  char* lB1 = lB0 + 4096;

  f32x4 acc[4][4];
#pragma unroll
  for (int i = 0; i < 4; ++i)
#pragma unroll
    for (int j = 0; j < 4; ++j) acc[i][j] = (f32x4){0.f, 0.f, 0.f, 0.f};

  const char* pa = (const char*)Asm + (wr * 64 + fr) * 64 + krow * 16;
  const char* pb = (const char*)Bsm + (wc * 64 + fr) * 64 + krow * 16;

  for (int kt = 0; kt < K / 32; ++kt) {
    __syncthreads();
    gload16(ga0 + kt * 32, lA0);
    gload16(ga1 + kt * 32, lA1);
    gload16(gb0 + kt * 32, lB0);
    gload16(gb1 + kt * 32, lB1);
    __syncthreads();

    bfrag8 af[4], bfv[4];
#pragma unroll
    for (int i = 0; i < 4; ++i) af[i] = *(const bfrag8*)(pa + i * 1024);
#pragma unroll
    for (int j = 0; j < 4; ++j) bfv[j] = *(const bfrag8*)(pb + j * 1024);
#pragma unroll
    for (int i = 0; i < 4; ++i)
#pragma unroll
      for (int j = 0; j < 4; ++j)
        acc[i][j] = __builtin_amdgcn_mfma_f32_16x16x32_bf16(af[i], bfv[j], acc[i][j], 0, 0, 0);
  }

  const int orow = (lane >> 4) * 4;
  const int ocol = lane & 15;
#pragma unroll
  for (int i = 0; i < 4; ++i) {
#pragma unroll
    for (int j = 0; j < 4; ++j) {
      const int gn = n0 + wc * 64 + j * 16 + ocol;
      const int gm0 = m0 + wr * 64 + i * 16 + orow;
      if (EPI == 0) {
        const int which = gn >> 10, hh = (gn >> 6) & 15, e = gn & 63;
        const int bb = gm0 >> 10, s0 = gm0 & 1023;
        const int hb = hh * 4 + bb;
        u16* oq = (u16*)Cout;
        if (which == 0) {
#pragma unroll
          for (int r = 0; r < 4; ++r)
            oq[((size_t)hb * 1024 + s0 + r) * 64 + e] = f2bf(acc[i][j][r] * QSCALE);
        } else if (which == 1) {
#pragma unroll
          for (int r = 0; r < 4; ++r)
            oq[4194304 + ((size_t)hb * 1024 + s0 + r) * 64 + e] = f2bf(acc[i][j][r]);
        } else {
          ushort4 pk = make_ushort4(f2bf(acc[i][j][0]), f2bf(acc[i][j][1]),
                                    f2bf(acc[i][j][2]), f2bf(acc[i][j][3]));
          *(ushort4*)&oq[8388608 + ((size_t)hb * 64 + e) * 1024 + s0] = pk;
        }
      } else if (EPI == 1) {
#pragma unroll
        for (int r = 0; r < 4; ++r) {
          float v = fmaxf(acc[i][j][r] + bias[gn], 0.f);
          ((u16*)Cout)[(size_t)(gm0 + r) * N + gn] = f2bf(v);
        }
      } else {
#pragma unroll
        for (int r = 0; r < 4; ++r)
          ((float*)Cout)[(size_t)(gm0 + r) * N + gn] = acc[i][j][r] + bias[gn];
      }
    }
  }
}

// ---------------------------------------------------------------------------
// bf16 MFMA GEMM, 128x64 tile (for small-N FFN2): 4 waves x (32x64), BK=32.
// ---------------------------------------------------------------------------
__global__ __launch_bounds__(256) void mfma_gemm_n64(
    const u16* __restrict__ A, const u16* __restrict__ Bt,
    const float* __restrict__ bias, float* __restrict__ Cout, int N, int K) {
  __shared__ alignas(16) u16 Asm[128 * 32];
  __shared__ alignas(16) u16 Bsm[64 * 32];
  const int tid = threadIdx.x;
  const int wid = tid >> 6, lane = tid & 63;
  const int nid = xcd_swz();
  const int m0 = (nid / gridDim.x) * 128, n0 = (nid % gridDim.x) * 64;
  const int fr = lane & 15, krow = lane >> 4;

  const int srow = tid >> 2;
  const int sk = (tid & 3) * 8;
  const u16* ga0 = A + (size_t)(m0 + srow) * K + sk;
  const u16* ga1 = A + (size_t)(m0 + srow + 64) * K + sk;
  const u16* gb0 = Bt + (size_t)(n0 + srow) * K + sk;
  char* lA0 = (char*)Asm + tid * 16;
  char* lA1 = lA0 + 4096;
  char* lB0 = (char*)Bsm + tid * 16;

  f32x4 acc[2][4];
#pragma unroll
  for (int i = 0; i < 2; ++i)
#pragma unroll
    for (int j = 0; j < 4; ++j) acc[i][j] = (f32x4){0.f, 0.f, 0.f, 0.f};

  const char* pa = (const char*)Asm + (wid * 32 + fr) * 64 + krow * 16;
  const char* pb = (const char*)Bsm + fr * 64 + krow * 16;

  for (int kt = 0; kt < K / 32; ++kt) {
    __syncthreads();
    gload16(ga0 + kt * 32, lA0);
    gload16(ga1 + kt * 32, lA1);
    gload16(gb0 + kt * 32, lB0);
    __syncthreads();

    bfrag8 af[2], bfv[4];
#pragma unroll
    for (int i = 0; i < 2; ++i) af[i] = *(const bfrag8*)(pa + i * 1024);
#pragma unroll
    for (int j = 0; j < 4; ++j) bfv[j] = *(const bfrag8*)(pb + j * 1024);
#pragma unroll
    for (int i = 0; i < 2; ++i)
#pragma unroll
      for (int j = 0; j < 4; ++j)
        acc[i][j] = __builtin_amdgcn_mfma_f32_16x16x32_bf16(af[i], bfv[j], acc[i][j], 0, 0, 0);
  }

  const int orow = (lane >> 4) * 4;
  const int ocol = lane & 15;
#pragma unroll
  for (int i = 0; i < 2; ++i)
#pragma unroll
    for (int j = 0; j < 4; ++j) {
      const int gn = n0 + j * 16 + ocol;
      const int gm0 = m0 + wid * 32 + i * 16 + orow;
#pragma unroll
      for (int r = 0; r < 4; ++r)
        Cout[(size_t)(gm0 + r) * N + gn] = acc[i][j][r] + bias[gn];
    }
}

// ---------------------------------------------------------------------------
// 32x32x16 swapped flash attention. Wave = 32 queries; block = 4 independent
// waves; grid = (8, 64) XCD-swizzled (one hb's 8 blocks stay on one XCD;
// K+V per hb = 256 KB -> 8 hb x 256 KB = 2 MB per XCD L2).
//
// Layouts (v_mfma_f32_32x32x16_bf16):
//   A: row = lane&31, k = (lane>>5)*8 + j   (8 contiguous k per lane)
//   B: col = lane&31, k = (lane>>5)*8 + j
//   C/D: col = lane&31, row = (reg&3) + 8*(reg>>2) + 4*(lane>>5)  [m74/m101]
//
// QK^T swapped: pa = mfma(K_frag, Q_frag) -> P[k][q], col q = lane&31:
//   lane holds 32 P-values of ONE query (16 per k-block; partner lane^32 has
//   the other 32). Softmax: in-lane tree + one shfl_xor(32).
// P -> PV B-frag (B[k][q], k=(lane>>5)*8+j): per k-block per 16k-step,
//   4 cvt_pk words + 2 permlane32_swap give exactly the needed k-halves:
//   own (k0..3 / k12..15) stays, partner's (k4..7 / k8..11) swaps in.
// PV swapped: po = mfma(Vt_frag, P_frag) -> O[e][q], col q = lane&31:
//   rescale = one scalar mul per reg; epilogue 8B stores per reg-quad.
// ---------------------------------------------------------------------------
__global__ __launch_bounds__(256, 2) void attn_mfma32(
    const u16* __restrict__ qb, const u16* __restrict__ kb,
    const u16* __restrict__ vtb, u16* __restrict__ h1) {
  const int wid = threadIdx.x >> 6, lane = threadIdx.x & 63;
  const int nid = xcd_swz();
  const int qx = nid & 7, hb = nid >> 3;
  const int h = hb >> 2, b = hb & 3;
  const int q0 = qx * 128 + wid * 32;
  const int ql = lane & 31, hi = lane >> 5;

  const u16* Qp  = qb + ((size_t)hb * 1024 + q0 + ql) * 64 + hi * 8;
  const u16* Kp0 = kb + (size_t)hb * 65536 + (size_t)ql * 64 + hi * 8;
  const u16* Kp1 = Kp0 + 32 * 64;
  const u16* Vp0 = vtb + (size_t)hb * 65536 + (size_t)ql * 1024 + hi * 8;
  const u16* Vp1 = Vp0 + 32 * 1024;

  // Q B-frags (fixed): B[k=st*16+hi*8+j][q=ql] = Q[q0+ql][dh], pre-scaled
  bfrag8 qf[4];
#pragma unroll
  for (int st = 0; st < 4; ++st) qf[st] = *(const bfrag8*)(Qp + st * 16);

  f32x16 po0, po1;
#pragma unroll
  for (int i = 0; i < 16; ++i) { po0[i] = 0.f; po1[i] = 0.f; }
  float mrun = -1e30f, lrun = 0.f;

  // builds one PV B-frag from 8 exp'd P-values p[base..base+7]
#define PACK4(dst, p, base)                                                    \
  {                                                                            \
    int a0, a1, b0, b1;                                                        \
    asm("v_cvt_pk_bf16_f32 %0, %1, %2" : "=v"(a0)                              \
        : "v"(p[base + 0]), "v"(p[base + 1]));                                 \
    asm("v_cvt_pk_bf16_f32 %0, %1, %2" : "=v"(a1)                              \
        : "v"(p[base + 2]), "v"(p[base + 3]));                                 \
    asm("v_cvt_pk_bf16_f32 %0, %1, %2" : "=v"(b0)                              \
        : "v"(p[base + 4]), "v"(p[base + 5]));                                 \
    asm("v_cvt_pk_bf16_f32 %0, %1, %2" : "=v"(b1)                              \
        : "v"(p[base + 6]), "v"(p[base + 7]));                                 \
    asm("v_permlane32_swap_b32 %0, %1" : "+v"(a0), "+v"(b0));                  \
    asm("v_permlane32_swap_b32 %0, %1" : "+v"(a1), "+v"(b1));                  \
    ix4 t = (ix4){a0, a1, b0, b1};                                             \
    dst = __builtin_bit_cast(bfrag8, t);                                       \
  }

  for (int kt = 0; kt < 16; ++kt) {
    const u16* k0 = Kp0 + kt * 4096;
    const u16* k1 = Kp1 + kt * 4096;
    const u16* v0 = Vp0 + kt * 64;
    const u16* v1 = Vp1 + kt * 64;
    bfrag8 kf0[4], kf1[4], vf0[4], vf1[4];
#pragma unroll
    for (int st = 0; st < 4; ++st) {
      kf0[st] = *(const bfrag8*)(k0 + st * 16);
      kf1[st] = *(const bfrag8*)(k1 + st * 16);
      vf0[st] = *(const bfrag8*)(v0 + st * 16);
      vf1[st] = *(const bfrag8*)(v1 + st * 16);
    }

    f32x16 pa0, pa1;
#pragma unroll
    for (int i = 0; i < 16; ++i) { pa0[i] = 0.f; pa1[i] = 0.f; }
    __builtin_amdgcn_s_setprio(1);
#pragma unroll
    for (int st = 0; st < 4; ++st) {
      pa0 = __builtin_amdgcn_mfma_f32_32x32x16_bf16(kf0[st], qf[st], pa0, 0, 0, 0);
      pa1 = __builtin_amdgcn_mfma_f32_32x32x16_bf16(kf1[st], qf[st], pa1, 0, 0, 0);
    }
    __builtin_amdgcn_s_setprio(0);

    // online softmax for query ql (exp2 domain; scale folded into q)
    float cm = fmaxf(pa0[0], pa1[0]);
#pragma unroll
    for (int i = 1; i < 16; ++i) cm = fmaxf(cm, fmaxf(pa0[i], pa1[i]));
    cm = fmaxf(cm, __shfl_xor(cm, 32));
    const float mnew = fmaxf(mrun, cm);
    const float scl = exp2f(mrun - mnew);
    mrun = mnew;
    float psum = 0.f;
#pragma unroll
    for (int i = 0; i < 16; ++i) {
      pa0[i] = exp2f(pa0[i] - mnew);
      pa1[i] = exp2f(pa1[i] - mnew);
      psum += pa0[i] + pa1[i];
    }
    psum += __shfl_xor(psum, 32);
    lrun = lrun * scl + psum;
    po0 *= scl;
    po1 *= scl;

    // P -> bf16 B-frags (k-steps 0..3 of 16 within this 64-key tile)
    bfrag8 pf00, pf01, pf10, pf11;
    PACK4(pf00, pa0, 0);
    PACK4(pf01, pa0, 8);
    PACK4(pf10, pa1, 0);
    PACK4(pf11, pa1, 8);

    __builtin_amdgcn_s_setprio(1);
    po0 = __builtin_amdgcn_mfma_f32_32x32x16_bf16(vf0[0], pf00, po0, 0, 0, 0);
    po0 = __builtin_amdgcn_mfma_f32_32x32x16_bf16(vf0[1], pf01, po0, 0, 0, 0);
    po0 = __builtin_amdgcn_mfma_f32_32x32x16_bf16(vf0[2], pf10, po0, 0, 0, 0);
    po0 = __builtin_amdgcn_mfma_f32_32x32x16_bf16(vf0[3], pf11, po0, 0, 0, 0);
    po1 = __builtin_amdgcn_mfma_f32_32x32x16_bf16(vf1[0], pf00, po1, 0, 0, 0);
    po1 = __builtin_amdgcn_mfma_f32_32x32x16_bf16(vf1[1], pf01, po1, 0, 0, 0);
    po1 = __builtin_amdgcn_mfma_f32_32x32x16_bf16(vf1[2], pf10, po1, 0, 0, 0);
    po1 = __builtin_amdgcn_mfma_f32_32x32x16_bf16(vf1[3], pf11, po1, 0, 0, 0);
    __builtin_amdgcn_s_setprio(0);
  }
#undef PACK4

  // epilogue: O[e][q]/l; reg rr of quad r4 holds e = eb*32 + r4*8 + hi*4 + rr
  const float inv = 1.f / lrun;
  u16* orow = h1 + ((size_t)(b * 1024 + q0 + ql)) * 1024 + h * 64 + hi * 4;
#pragma unroll
  for (int r4 = 0; r4 < 4; ++r4) {
    ushort4 o0 = make_ushort4(
        f2bf(po0[r4 * 4 + 0] * inv), f2bf(po0[r4 * 4 + 1] * inv),
        f2bf(po0[r4 * 4 + 2] * inv), f2bf(po0[r4 * 4 + 3] * inv));
    *(ushort4*)(orow + r4 * 8) = o0;
    ushort4 o1 = make_ushort4(
        f2bf(po1[r4 * 4 + 0] * inv), f2bf(po1[r4 * 4 + 1] * inv),
        f2bf(po1[r4 * 4 + 2] * inv), f2bf(po1[r4 * 4 + 3] * inv));
    *(ushort4*)(orow + 32 + r4 * 8) = o1;
  }
}

// ---------------------------------------------------------------------------
extern "C" void kernel_launch(void* const* d_in, const int* in_sizes, int n_in,
                              void* d_out, int out_size, void* d_ws, size_t ws_size,
                              hipStream_t stream) {
  const float* x  = (const float*)d_in[0];
  const float* Wq = (const float*)d_in[1];
  const float* Wk = (const float*)d_in[2];
  const float* Wv = (const float*)d_in[3];
  const float* W1 = (const float*)d_in[4];
  const float* b1 = (const float*)d_in[5];
  const float* W2 = (const float*)d_in[6];
  const float* b2 = (const float*)d_in[7];

  const size_t MB = 1u << 20;
  char* w = (char*)d_ws;
  u16* qkvb  = (u16*)w;                    // 24 MB: q | k | vT
  u16* Xb    = (u16*)(w + 24 * MB);
  u16* Wqkvt = (u16*)(w + 32 * MB);
  u16* W1t   = (u16*)(w + 38 * MB);
  u16* W2t   = (u16*)(w + 42 * MB);
  u16* h1b   = (u16*)(w + 46 * MB);
  u16* ffb   = (u16*)(w + 54 * MB);

  cvt_bf16<<<4096, 256, 0, stream>>>(x, Xb, 1048576);
  qkv_transpose_cvt<<<dim3(16, 48), 256, 0, stream>>>(Wq, Wk, Wv, Wqkvt);
  transpose_cvt<<<dim3(16, 32), 256, 0, stream>>>(W1, W1t, 1024, 2048);
  transpose_cvt<<<dim3(32, 16), 256, 0, stream>>>(W2, W2t, 2048, 1024);

  // QKV: [4096,1024] @ [1024,3072] -> bf16 q(scaled)/k/vT scatter
  mfma_gemm<0><<<dim3(24, 32), 256, 0, stream>>>(Xb, Wqkvt, nullptr, qkvb, 3072, 1024);
  // attention -> h1b bf16 [4096][1024]
  attn_mfma32<<<dim3(8, 64), 256, 0, stream>>>(qkvb, qkvb + 4194304, qkvb + 8388608, h1b);
  // FFN1: relu(h1 @ W1 + b1) -> ffb bf16 [4096][2048]
  mfma_gemm<1><<<dim3(16, 32), 256, 0, stream>>>(h1b, W1t, b1, ffb, 2048, 1024);
  // FFN2: ff @ W2 + b2 -> out fp32 [4096][1024], 128x64 tiles (2 blk/CU)
  mfma_gemm_n64<<<dim3(16, 32), 256, 0, stream>>>(ffb, W2t, b2, (float*)d_out, 1024, 2048);
}

// Round 7
// 269.821 us; speedup vs baseline: 1.0342x; 1.0195x over previous
//
#include <hip/hip_runtime.h>
#include <hip/hip_bf16.h>

// EncoderLayer: B=4 S=1024 D=1024 H=16 DH=64 DFF=2048
// Round 7: (1) coalesced QKV epilogue + separate vT transpose kernel
//          (2) attn: K reg-double-buffer + early V loads (latency hiding)
//          (3) attn: tree-structured softmax reductions + T13 deferred rescale
//
// ws layout (bytes):
//   qkvb bf16: q|k|v each [64hb][1024][64]   @ 0     (24 MB)
//      (q pre-scaled by 0.125*log2e for exp2-domain softmax)
//   vtb  bf16 [64hb][64][1024]               @ 24 MB (8 MB)
//   Xb    bf16 [4096][1024]                  @ 32 MB (8 MB)
//   Wqkvt bf16 [3072][1024]  (B^T)           @ 40 MB (6 MB)
//   W1t   bf16 [2048][1024]  (B^T)           @ 46 MB (4 MB)
//   W2t   bf16 [1024][2048]  (B^T)           @ 50 MB (4 MB)
//   h1b   bf16 [4096][1024]                  @ 54 MB (8 MB)
//   ffb   bf16 [4096][2048]                  @ 62 MB (16 MB)  -> 78 MB total

typedef unsigned short u16;
typedef __attribute__((ext_vector_type(8))) short bfrag8;    // 8 bf16 = 4 VGPRs
typedef __attribute__((ext_vector_type(4))) float f32x4;
typedef __attribute__((ext_vector_type(16))) float f32x16;
typedef __attribute__((ext_vector_type(4))) int ix4;

constexpr int Bb = 4, Ss = 1024, Dd = 1024, Hh = 16, DFF = 2048;
constexpr float QSCALE = 0.18033688011112042f;   // 0.125 * log2(e)

__device__ __forceinline__ u16 f2bf(float f) {
  unsigned u = __float_as_uint(f);
  return (u16)((u + 0x7fffu + ((u >> 16) & 1u)) >> 16);
}

__device__ __forceinline__ void gload16(const void* g, void* l) {
  __builtin_amdgcn_global_load_lds(
      (const __attribute__((address_space(1))) unsigned int*)g,
      (__attribute__((address_space(3))) unsigned int*)l, 16, 0, 0);
}

// chunked XCD swizzle: hw block id -> work id (grid size % 8 == 0)
__device__ __forceinline__ int xcd_swz() {
  const int id = blockIdx.y * gridDim.x + blockIdx.x;
  const int cpx = (gridDim.x * gridDim.y) >> 3;
  return (id & 7) * cpx + (id >> 3);
}

// ---------------------------------------------------------------------------
__global__ __launch_bounds__(256) void cvt_bf16(const float* __restrict__ in,
                                                u16* __restrict__ out, int n4) {
  int i = blockIdx.x * 256 + threadIdx.x;
  if (i >= n4) return;
  float4 v = ((const float4*)in)[i];
  ushort4 o = make_ushort4(f2bf(v.x), f2bf(v.y), f2bf(v.z), f2bf(v.w));
  *(ushort4*)(out + (size_t)i * 4) = o;
}

__device__ __forceinline__ void transpose64(const float* __restrict__ in,
                                            u16* __restrict__ out,
                                            int R, int C, int r0, int c0) {
  __shared__ float tile[64][65];
  const int t = threadIdx.x, cl = t & 63, rq = t >> 6;
#pragma unroll
  for (int i = 0; i < 16; ++i) {
    int rl = rq * 16 + i;
    tile[rl][cl] = in[(size_t)(r0 + rl) * C + c0 + cl];
  }
  __syncthreads();
#pragma unroll
  for (int i = 0; i < 16; ++i) {
    int oc = rq * 16 + i;
    out[(size_t)(c0 + oc) * R + r0 + cl] = f2bf(tile[cl][oc]);
  }
}

__global__ __launch_bounds__(256) void transpose_cvt(const float* __restrict__ in,
                                                     u16* __restrict__ out,
                                                     int R, int C) {
  transpose64(in, out, R, C, blockIdx.x * 64, blockIdx.y * 64);
}

__global__ __launch_bounds__(256) void qkv_transpose_cvt(
    const float* __restrict__ Wq, const float* __restrict__ Wk,
    const float* __restrict__ Wv, u16* __restrict__ out) {
  const int z = blockIdx.y;            // 0..47
  const int which = z >> 4, h = z & 15;
  const float* in = (which == 0 ? Wq : which == 1 ? Wk : Wv) + (size_t)h * 1024 * 64;
  u16* o = out + (size_t)z * 64 * 1024;
  transpose64(in, o, 1024, 64, blockIdx.x * 64, 0);
}

// v [hb][1024][64] bf16 -> vT [hb][64][1024] bf16. grid (16, 64).
// Coalesced global in/out; LDS [64][65] fp32 (exact bf16 roundtrip),
// write conflict-free, read 2-way (free).
__global__ __launch_bounds__(256) void vt_transpose(const u16* __restrict__ in,
                                                    u16* __restrict__ out) {
  __shared__ float tile[64][65];
  const int hb = blockIdx.y, s0 = blockIdx.x * 64;
  const int t = threadIdx.x, cl = t & 63, rq = t >> 6;
#pragma unroll
  for (int i = 0; i < 16; ++i) {
    const int rl = rq * 16 + i;
    tile[rl][cl] = __uint_as_float(
        (unsigned)in[((size_t)hb * 1024 + s0 + rl) * 64 + cl] << 16);
  }
  __syncthreads();
#pragma unroll
  for (int i = 0; i < 16; ++i) {
    const int oc = rq * 16 + i;
    out[((size_t)hb * 64 + oc) * 1024 + s0 + cl] =
        (u16)(__float_as_uint(tile[cl][oc]) >> 16);
  }
}

// ---------------------------------------------------------------------------
// bf16 MFMA GEMM, 128x128 tile, BK=32, 4 waves x (64x64).
// EPI 0: coalesced bf16 q(scaled)/k/v scatter to [hb][s][64];
//     1: +bias,relu -> bf16; 2: +bias -> fp32.
// ---------------------------------------------------------------------------
template <int EPI>
__global__ __launch_bounds__(256) void mfma_gemm(
    const u16* __restrict__ A, const u16* __restrict__ Bt,
    const float* __restrict__ bias, void* __restrict__ Cout, int N, int K) {
  __shared__ alignas(16) u16 Asm[128 * 32];   // [row][k], row stride 64 B
  __shared__ alignas(16) u16 Bsm[128 * 32];
  const int tid = threadIdx.x;
  const int wid = tid >> 6, lane = tid & 63;
  const int nid = xcd_swz();
  const int m0 = (nid / gridDim.x) * 128, n0 = (nid % gridDim.x) * 128;
  const int wr = wid >> 1, wc = wid & 1;
  const int fr = lane & 15, krow = lane >> 4;

  const int srow = tid >> 2;
  const int sk = (tid & 3) * 8;
  const u16* ga0 = A + (size_t)(m0 + srow) * K + sk;
  const u16* ga1 = A + (size_t)(m0 + srow + 64) * K + sk;
  const u16* gb0 = Bt + (size_t)(n0 + srow) * K + sk;
  const u16* gb1 = Bt + (size_t)(n0 + srow + 64) * K + sk;
  char* lA0 = (char*)Asm + tid * 16;
  char* lA1 = lA0 + 4096;
  char* lB0 = (char*)Bsm + tid * 16;
  char* lB1 = lB0 + 4096;

  f32x4 acc[4][4];
#pragma unroll
  for (int i = 0; i < 4; ++i)
#pragma unroll
    for (int j = 0; j < 4; ++j) acc[i][j] = (f32x4){0.f, 0.f, 0.f, 0.f};

  const char* pa = (const char*)Asm + (wr * 64 + fr) * 64 + krow * 16;
  const char* pb = (const char*)Bsm + (wc * 64 + fr) * 64 + krow * 16;

  for (int kt = 0; kt < K / 32; ++kt) {
    __syncthreads();
    gload16(ga0 + kt * 32, lA0);
    gload16(ga1 + kt * 32, lA1);
    gload16(gb0 + kt * 32, lB0);
    gload16(gb1 + kt * 32, lB1);
    __syncthreads();

    bfrag8 af[4], bfv[4];
#pragma unroll
    for (int i = 0; i < 4; ++i) af[i] = *(const bfrag8*)(pa + i * 1024);
#pragma unroll
    for (int j = 0; j < 4; ++j) bfv[j] = *(const bfrag8*)(pb + j * 1024);
#pragma unroll
    for (int i = 0; i < 4; ++i)
#pragma unroll
      for (int j = 0; j < 4; ++j)
        acc[i][j] = __builtin_amdgcn_mfma_f32_16x16x32_bf16(af[i], bfv[j], acc[i][j], 0, 0, 0);
  }

  const int orow = (lane >> 4) * 4;
  const int ocol = lane & 15;
#pragma unroll
  for (int i = 0; i < 4; ++i) {
#pragma unroll
    for (int j = 0; j < 4; ++j) {
      const int gn = n0 + wc * 64 + j * 16 + ocol;
      const int gm0 = m0 + wr * 64 + i * 16 + orow;
      if (EPI == 0) {
        const int which = gn >> 10, hh = (gn >> 6) & 15, e = gn & 63;
        const int bb = gm0 >> 10, s0 = gm0 & 1023;
        const int hb = hh * 4 + bb;
        u16* oq = (u16*)Cout + (size_t)which * 4194304 +
                  ((size_t)hb * 1024 + s0) * 64 + e;
        const float sc = (which == 0) ? QSCALE : 1.f;
#pragma unroll
        for (int r = 0; r < 4; ++r) oq[r * 64] = f2bf(acc[i][j][r] * sc);
      } else if (EPI == 1) {
#pragma unroll
        for (int r = 0; r < 4; ++r) {
          float v = fmaxf(acc[i][j][r] + bias[gn], 0.f);
          ((u16*)Cout)[(size_t)(gm0 + r) * N + gn] = f2bf(v);
        }
      } else {
#pragma unroll
        for (int r = 0; r < 4; ++r)
          ((float*)Cout)[(size_t)(gm0 + r) * N + gn] = acc[i][j][r] + bias[gn];
      }
    }
  }
}

// ---------------------------------------------------------------------------
// bf16 MFMA GEMM, 128x64 tile (for small-N FFN2): 4 waves x (32x64), BK=32.
// ---------------------------------------------------------------------------
__global__ __launch_bounds__(256) void mfma_gemm_n64(
    const u16* __restrict__ A, const u16* __restrict__ Bt,
    const float* __restrict__ bias, float* __restrict__ Cout, int N, int K) {
  __shared__ alignas(16) u16 Asm[128 * 32];
  __shared__ alignas(16) u16 Bsm[64 * 32];
  const int tid = threadIdx.x;
  const int wid = tid >> 6, lane = tid & 63;
  const int nid = xcd_swz();
  const int m0 = (nid / gridDim.x) * 128, n0 = (nid % gridDim.x) * 64;
  const int fr = lane & 15, krow = lane >> 4;

  const int srow = tid >> 2;
  const int sk = (tid & 3) * 8;
  const u16* ga0 = A + (size_t)(m0 + srow) * K + sk;
  const u16* ga1 = A + (size_t)(m0 + srow + 64) * K + sk;
  const u16* gb0 = Bt + (size_t)(n0 + srow) * K + sk;
  char* lA0 = (char*)Asm + tid * 16;
  char* lA1 = lA0 + 4096;
  char* lB0 = (char*)Bsm + tid * 16;

  f32x4 acc[2][4];
#pragma unroll
  for (int i = 0; i < 2; ++i)
#pragma unroll
    for (int j = 0; j < 4; ++j) acc[i][j] = (f32x4){0.f, 0.f, 0.f, 0.f};

  const char* pa = (const char*)Asm + (wid * 32 + fr) * 64 + krow * 16;
  const char* pb = (const char*)Bsm + fr * 64 + krow * 16;

  for (int kt = 0; kt < K / 32; ++kt) {
    __syncthreads();
    gload16(ga0 + kt * 32, lA0);
    gload16(ga1 + kt * 32, lA1);
    gload16(gb0 + kt * 32, lB0);
    __syncthreads();

    bfrag8 af[2], bfv[4];
#pragma unroll
    for (int i = 0; i < 2; ++i) af[i] = *(const bfrag8*)(pa + i * 1024);
#pragma unroll
    for (int j = 0; j < 4; ++j) bfv[j] = *(const bfrag8*)(pb + j * 1024);
#pragma unroll
    for (int i = 0; i < 2; ++i)
#pragma unroll
      for (int j = 0; j < 4; ++j)
        acc[i][j] = __builtin_amdgcn_mfma_f32_16x16x32_bf16(af[i], bfv[j], acc[i][j], 0, 0, 0);
  }

  const int orow = (lane >> 4) * 4;
  const int ocol = lane & 15;
#pragma unroll
  for (int i = 0; i < 2; ++i)
#pragma unroll
    for (int j = 0; j < 4; ++j) {
      const int gn = n0 + j * 16 + ocol;
      const int gm0 = m0 + wid * 32 + i * 16 + orow;
#pragma unroll
      for (int r = 0; r < 4; ++r)
        Cout[(size_t)(gm0 + r) * N + gn] = acc[i][j][r] + bias[gn];
    }
}

// ---------------------------------------------------------------------------
// 32x32x16 swapped flash attention (round-6 layouts, verified) +
// K register double-buffer, early V loads, tree reductions, T13 defer-max.
// Wave = 32 queries; block = 4 independent waves; grid = (8, 64) swizzled.
// ---------------------------------------------------------------------------
__global__ __launch_bounds__(256, 2) void attn_mfma32(
    const u16* __restrict__ qb, const u16* __restrict__ kb,
    const u16* __restrict__ vtb, u16* __restrict__ h1) {
  const int wid = threadIdx.x >> 6, lane = threadIdx.x & 63;
  const int nid = xcd_swz();
  const int qx = nid & 7, hb = nid >> 3;
  const int h = hb >> 2, b = hb & 3;
  const int q0 = qx * 128 + wid * 32;
  const int ql = lane & 31, hi = lane >> 5;

  const u16* Qp = qb + ((size_t)hb * 1024 + q0 + ql) * 64 + hi * 8;
  const u16* Kp = kb + (size_t)hb * 65536 + (size_t)ql * 64 + hi * 8;
  const u16* Vp = vtb + (size_t)hb * 65536 + (size_t)ql * 1024 + hi * 8;

  bfrag8 qf[4];
#pragma unroll
  for (int st = 0; st < 4; ++st) qf[st] = *(const bfrag8*)(Qp + st * 16);

  f32x16 po0, po1;
#pragma unroll
  for (int i = 0; i < 16; ++i) { po0[i] = 0.f; po1[i] = 0.f; }
  float mrun = -1e30f, lrun = 0.f;

  bfrag8 kA[8], kB[8], vv[8];

#define LOADK(dst, kt)                                                         \
  {                                                                            \
    _Pragma("unroll") for (int st = 0; st < 4; ++st) {                         \
      dst[st]     = *(const bfrag8*)(Kp + (size_t)(kt) * 4096 + st * 16);      \
      dst[4 + st] = *(const bfrag8*)(Kp + (size_t)(kt) * 4096 + 2048 + st * 16); \
    }                                                                          \
  }
#define LOADV(dst, kt)                                                         \
  {                                                                            \
    _Pragma("unroll") for (int st = 0; st < 4; ++st) {                         \
      dst[st]     = *(const bfrag8*)(Vp + (kt) * 64 + st * 16);                \
      dst[4 + st] = *(const bfrag8*)(Vp + 32768 + (kt) * 64 + st * 16);        \
    }                                                                          \
  }

#define PACK4(dst, p, base)                                                    \
  {                                                                            \
    int a0, a1, b0, b1;                                                        \
    asm("v_cvt_pk_bf16_f32 %0, %1, %2" : "=v"(a0)                              \
        : "v"(p[base + 0]), "v"(p[base + 1]));                                 \
    asm("v_cvt_pk_bf16_f32 %0, %1, %2" : "=v"(a1)                              \
        : "v"(p[base + 2]), "v"(p[base + 3]));                                 \
    asm("v_cvt_pk_bf16_f32 %0, %1, %2" : "=v"(b0)                              \
        : "v"(p[base + 4]), "v"(p[base + 5]));                                 \
    asm("v_cvt_pk_bf16_f32 %0, %1, %2" : "=v"(b1)                              \
        : "v"(p[base + 6]), "v"(p[base + 7]));                                 \
    asm("v_permlane32_swap_b32 %0, %1" : "+v"(a0), "+v"(b0));                  \
    asm("v_permlane32_swap_b32 %0, %1" : "+v"(a1), "+v"(b1));                  \
    ix4 t = (ix4){a0, a1, b0, b1};                                             \
    dst = __builtin_bit_cast(bfrag8, t);                                       \
  }

#define STEP(kf)                                                               \
  {                                                                            \
    f32x16 pa0, pa1;                                                           \
    _Pragma("unroll") for (int i = 0; i < 16; ++i) { pa0[i] = 0.f; pa1[i] = 0.f; } \
    __builtin_amdgcn_s_setprio(1);                                             \
    _Pragma("unroll") for (int st = 0; st < 4; ++st) {                         \
      pa0 = __builtin_amdgcn_mfma_f32_32x32x16_bf16(kf[st], qf[st], pa0, 0, 0, 0); \
      pa1 = __builtin_amdgcn_mfma_f32_32x32x16_bf16(kf[4 + st], qf[st], pa1, 0, 0, 0); \
    }                                                                          \
    __builtin_amdgcn_s_setprio(0);                                             \
    float t4[8];                                                               \
    _Pragma("unroll") for (int g = 0; g < 4; ++g) {                            \
      t4[g] = fmaxf(fmaxf(pa0[4 * g], pa0[4 * g + 1]),                         \
                    fmaxf(pa0[4 * g + 2], pa0[4 * g + 3]));                    \
      t4[4 + g] = fmaxf(fmaxf(pa1[4 * g], pa1[4 * g + 1]),                     \
                        fmaxf(pa1[4 * g + 2], pa1[4 * g + 3]));                \
    }                                                                          \
    float cm = fmaxf(fmaxf(fmaxf(t4[0], t4[1]), fmaxf(t4[2], t4[3])),          \
                     fmaxf(fmaxf(t4[4], t4[5]), fmaxf(t4[6], t4[7])));         \
    cm = fmaxf(cm, __shfl_xor(cm, 32));                                        \
    if (__any(cm > mrun + 8.f)) {   /* T13: rescale only on real max growth */ \
      const float mnew = fmaxf(mrun, cm);                                      \
      const float scl = exp2f(mrun - mnew);                                    \
      mrun = mnew;                                                             \
      lrun *= scl;                                                             \
      po0 *= scl;                                                              \
      po1 *= scl;                                                              \
    }                                                                          \
    _Pragma("unroll") for (int i = 0; i < 16; ++i) {                           \
      pa0[i] = exp2f(pa0[i] - mrun);                                           \
      pa1[i] = exp2f(pa1[i] - mrun);                                           \
    }                                                                          \
    float s4[8];                                                               \
    _Pragma("unroll") for (int g = 0; g < 4; ++g) {                            \
      s4[g] = (pa0[4 * g] + pa0[4 * g + 1]) + (pa0[4 * g + 2] + pa0[4 * g + 3]); \
      s4[4 + g] = (pa1[4 * g] + pa1[4 * g + 1]) + (pa1[4 * g + 2] + pa1[4 * g + 3]); \
    }                                                                          \
    float psum = ((s4[0] + s4[1]) + (s4[2] + s4[3])) +                         \
                 ((s4[4] + s4[5]) + (s4[6] + s4[7]));                          \
    psum += __shfl_xor(psum, 32);                                              \
    lrun += psum;                                                              \
    bfrag8 pf00, pf01, pf10, pf11;                                             \
    PACK4(pf00, pa0, 0);                                                       \
    PACK4(pf01, pa0, 8);                                                       \
    PACK4(pf10, pa1, 0);                                                       \
    PACK4(pf11, pa1, 8);                                                       \
    __builtin_amdgcn_s_setprio(1);                                             \
    po0 = __builtin_amdgcn_mfma_f32_32x32x16_bf16(vv[0], pf00, po0, 0, 0, 0);  \
    po0 = __builtin_amdgcn_mfma_f32_32x32x16_bf16(vv[1], pf01, po0, 0, 0, 0);  \
    po0 = __builtin_amdgcn_mfma_f32_32x32x16_bf16(vv[2], pf10, po0, 0, 0, 0);  \
    po0 = __builtin_amdgcn_mfma_f32_32x32x16_bf16(vv[3], pf11, po0, 0, 0, 0);  \
    po1 = __builtin_amdgcn_mfma_f32_32x32x16_bf16(vv[4], pf00, po1, 0, 0, 0);  \
    po1 = __builtin_amdgcn_mfma_f32_32x32x16_bf16(vv[5], pf01, po1, 0, 0, 0);  \
    po1 = __builtin_amdgcn_mfma_f32_32x32x16_bf16(vv[6], pf10, po1, 0, 0, 0);  \
    po1 = __builtin_amdgcn_mfma_f32_32x32x16_bf16(vv[7], pf11, po1, 0, 0, 0);  \
    __builtin_amdgcn_s_setprio(0);                                             \
  }

  LOADK(kA, 0);
  for (int kt = 0; kt < 16; kt += 2) {
    LOADV(vv, kt);          // V for tile kt: latency hides under QK+softmax
    LOADK(kB, kt + 1);      // K prefetch: hides under full STEP
    STEP(kA);
    LOADV(vv, kt + 1);
    if (kt + 2 < 16) LOADK(kA, kt + 2);
    STEP(kB);
  }
#undef LOADK
#undef LOADV
#undef PACK4
#undef STEP

  // epilogue: O[e][q]/l; reg rr of quad r4 holds e = eb*32 + r4*8 + hi*4 + rr
  const float inv = 1.f / lrun;
  u16* orow = h1 + ((size_t)(b * 1024 + q0 + ql)) * 1024 + h * 64 + hi * 4;
#pragma unroll
  for (int r4 = 0; r4 < 4; ++r4) {
    ushort4 o0 = make_ushort4(
        f2bf(po0[r4 * 4 + 0] * inv), f2bf(po0[r4 * 4 + 1] * inv),
        f2bf(po0[r4 * 4 + 2] * inv), f2bf(po0[r4 * 4 + 3] * inv));
    *(ushort4*)(orow + r4 * 8) = o0;
    ushort4 o1 = make_ushort4(
        f2bf(po1[r4 * 4 + 0] * inv), f2bf(po1[r4 * 4 + 1] * inv),
        f2bf(po1[r4 * 4 + 2] * inv), f2bf(po1[r4 * 4 + 3] * inv));
    *(ushort4*)(orow + 32 + r4 * 8) = o1;
  }
}

// ---------------------------------------------------------------------------
extern "C" void kernel_launch(void* const* d_in, const int* in_sizes, int n_in,
                              void* d_out, int out_size, void* d_ws, size_t ws_size,
                              hipStream_t stream) {
  const float* x  = (const float*)d_in[0];
  const float* Wq = (const float*)d_in[1];
  const float* Wk = (const float*)d_in[2];
  const float* Wv = (const float*)d_in[3];
  const float* W1 = (const float*)d_in[4];
  const float* b1 = (const float*)d_in[5];
  const float* W2 = (const float*)d_in[6];
  const float* b2 = (const float*)d_in[7];

  const size_t MB = 1u << 20;
  char* w = (char*)d_ws;
  u16* qkvb  = (u16*)w;                    // 24 MB: q | k | v  ([hb][s][64])
  u16* vtb   = (u16*)(w + 24 * MB);        // 8 MB: [hb][64][1024]
  u16* Xb    = (u16*)(w + 32 * MB);
  u16* Wqkvt = (u16*)(w + 40 * MB);
  u16* W1t   = (u16*)(w + 46 * MB);
  u16* W2t   = (u16*)(w + 50 * MB);
  u16* h1b   = (u16*)(w + 54 * MB);
  u16* ffb   = (u16*)(w + 62 * MB);

  cvt_bf16<<<4096, 256, 0, stream>>>(x, Xb, 1048576);
  qkv_transpose_cvt<<<dim3(16, 48), 256, 0, stream>>>(Wq, Wk, Wv, Wqkvt);
  transpose_cvt<<<dim3(16, 32), 256, 0, stream>>>(W1, W1t, 1024, 2048);
  transpose_cvt<<<dim3(32, 16), 256, 0, stream>>>(W2, W2t, 2048, 1024);

  // QKV: [4096,1024] @ [1024,3072] -> bf16 q(scaled)/k/v coalesced scatter
  mfma_gemm<0><<<dim3(24, 32), 256, 0, stream>>>(Xb, Wqkvt, nullptr, qkvb, 3072, 1024);
  // v -> vT
  vt_transpose<<<dim3(16, 64), 256, 0, stream>>>(qkvb + 8388608, vtb);
  // attention -> h1b bf16 [4096][1024]
  attn_mfma32<<<dim3(8, 64), 256, 0, stream>>>(qkvb, qkvb + 4194304, vtb, h1b);
  // FFN1: relu(h1 @ W1 + b1) -> ffb bf16 [4096][2048]
  mfma_gemm<1><<<dim3(16, 32), 256, 0, stream>>>(h1b, W1t, b1, ffb, 2048, 1024);
  // FFN2: ff @ W2 + b2 -> out fp32 [4096][1024], 128x64 tiles (2 blk/CU)
  mfma_gemm_n64<<<dim3(16, 32), 256, 0, stream>>>(ffb, W2t, b2, (float*)d_out, 1024, 2048);
}